// Round 1
// baseline (350.347 us; speedup 1.0000x reference)
//
#include <hip/hip_runtime.h>

typedef __bf16 bf16_t;
typedef __bf16 bf16x4 __attribute__((ext_vector_type(4)));
typedef __bf16 bf16x8 __attribute__((ext_vector_type(8)));
typedef float f32x4 __attribute__((ext_vector_type(4)));

#define MFMA16(a, b, c) __builtin_amdgcn_mfma_f32_16x16x32_bf16(a, b, c, 0, 0, 0)

// Problem constants
#define F_W 128
#define ED 512
#define NH 8
#define HD 64
#define B_NW 512   // 8 * 64 windows

// LDS strides (elements). Chosen so byte offsets of b128 reads are 16B-aligned
// and bank conflicts are <=2-way (free).
#define XS_STRIDE 40    // x_s     [128][40]
#define WTS_STRIDE 40   // wt_s    [192][40]
#define QK_STRIDE 72    // q/k_lds [128][72]
#define VT_STRIDE 136   // vt_lds  [64][136]
#define P_STRIDE 136    // p_lds   [128][136]

// ---------------- prep: transpose + convert weights to bf16 ----------------
__global__ __launch_bounds__(256) void prep_kernel(
    const float* __restrict__ qkv_w,   // [512][1536]
    const float* __restrict__ proj_w,  // [512][512]
    bf16_t* __restrict__ qkv_wt,       // [1536][512]
    bf16_t* __restrict__ proj_wt) {    // [512][512] (transposed: [n][k])
    int idx = blockIdx.x * 256 + threadIdx.x;
    if (idx < 1536 * 512) {
        int n = idx >> 9, k = idx & 511;
        qkv_wt[idx] = (bf16_t)qkv_w[k * 1536 + n];
    }
    if (idx < 512 * 512) {
        int n = idx >> 9, k = idx & 511;
        proj_wt[idx] = (bf16_t)proj_w[k * 512 + n];
    }
}

// ---------------- fused QKV projection + windowed attention ----------------
// One block per (window, head). 256 threads = 4 waves; wave r owns rows
// [32r, 32r+32) of the 128-row window.
__global__ __launch_bounds__(256) void fused_attn_kernel(
    const float* __restrict__ x,        // [B_NW*F_W][ED] fp32
    const float* __restrict__ adj,      // [8][8][128][128] fp32
    const float* __restrict__ qkv_b,    // [1536]
    const bf16_t* __restrict__ qkv_wt,  // [1536][512] bf16 (n-major)
    bf16_t* __restrict__ attn_out) {    // [B_NW*F_W][ED] bf16
    __shared__ bf16_t smem[27136];
    // region1 [0,18432): phase A staging -> then Q,K -> then P
    bf16_t* x_s  = smem;            // [128][XS_STRIDE]   5120 elems
    bf16_t* wt_s = smem + 5120;     // [192][WTS_STRIDE]  7680 elems
    bf16_t* q_lds = smem;           // [128][QK_STRIDE]   9216 elems
    bf16_t* k_lds = smem + 9216;    // [128][QK_STRIDE]   9216 elems
    bf16_t* p_lds = smem;           // [128][P_STRIDE]   17408 elems (aliases q+k)
    // region2 [18432, 27136): V transposed, lives across whole kernel tail
    bf16_t* vt_lds = smem + 18432;  // [64][VT_STRIDE]    8704 elems

    const int tid  = threadIdx.x;
    const int wave = tid >> 6;
    const int lane = tid & 63;
    const int lrow = lane & 15;   // fragment row/col within 16
    const int lgrp = lane >> 4;   // k-group
    const int w = blockIdx.x >> 3;  // window index [0,512)
    const int h = blockIdx.x & 7;   // head
    const int bidx = w >> 6;        // batch index (nW = 64)

    const float* xw = x + (size_t)w * F_W * ED;

    // ---------------- Phase A: QKV GEMM (M=128, N=192, K=512) --------------
    f32x4 acc[2][12];
#pragma unroll
    for (int mf = 0; mf < 2; ++mf)
#pragma unroll
        for (int nf = 0; nf < 12; ++nf) acc[mf][nf] = (f32x4)0.0f;

    for (int kc = 0; kc < 16; ++kc) {
        const int k0 = kc * 32;
        __syncthreads();
        // stage x chunk [128][32] fp32 -> bf16
#pragma unroll
        for (int i = 0; i < 4; ++i) {
            int linear = tid + i * 256;          // [0,1024)
            int row = linear >> 3, f4 = linear & 7;
            const float4 v = *(const float4*)(xw + (size_t)row * ED + k0 + f4 * 4);
            bf16x4 bv = {(bf16_t)v.x, (bf16_t)v.y, (bf16_t)v.z, (bf16_t)v.w};
            *(bf16x4*)(x_s + row * XS_STRIDE + f4 * 4) = bv;
        }
        // stage weight chunk: rows n = s*64 + d (192 rows), cols k0..k0+32
#pragma unroll
        for (int i = 0; i < 3; ++i) {
            int linear = tid + i * 256;          // [0,768)
            int row = linear >> 2, seg = linear & 3;
            int ng = (row >> 6) * 512 + h * 64 + (row & 63);
            bf16x8 v = *(const bf16x8*)(qkv_wt + (size_t)ng * 512 + k0 + seg * 8);
            *(bf16x8*)(wt_s + row * WTS_STRIDE + seg * 8) = v;
        }
        __syncthreads();
        bf16x8 a[2], b[12];
#pragma unroll
        for (int mf = 0; mf < 2; ++mf)
            a[mf] = *(const bf16x8*)(x_s + (wave * 32 + mf * 16 + lrow) * XS_STRIDE + lgrp * 8);
#pragma unroll
        for (int nf = 0; nf < 12; ++nf)
            b[nf] = *(const bf16x8*)(wt_s + (nf * 16 + lrow) * WTS_STRIDE + lgrp * 8);
#pragma unroll
        for (int mf = 0; mf < 2; ++mf)
#pragma unroll
            for (int nf = 0; nf < 12; ++nf)
                acc[mf][nf] = MFMA16(a[mf], b[nf], acc[mf][nf]);
    }
    __syncthreads();  // staging region dead; safe to overwrite with Q/K

    // ------------- write Q (scaled), K, V^T to LDS with bias ---------------
#pragma unroll
    for (int mf = 0; mf < 2; ++mf) {
#pragma unroll
        for (int nf = 0; nf < 12; ++nf) {
            int s = nf >> 2;
            int dl = (nf & 3) * 16 + lrow;  // head-dim index [0,64)
            float bias = qkv_b[s * 512 + h * 64 + dl];
#pragma unroll
            for (int j = 0; j < 4; ++j) {
                int row = wave * 32 + mf * 16 + lgrp * 4 + j;
                float val = acc[mf][nf][j] + bias;
                if (s == 0)      q_lds[row * QK_STRIDE + dl] = (bf16_t)(val * 0.125f);
                else if (s == 1) k_lds[row * QK_STRIDE + dl] = (bf16_t)val;
                else             vt_lds[dl * VT_STRIDE + row] = (bf16_t)val;
            }
        }
    }
    __syncthreads();

    // ---------------- Phase B: S = Q @ K^T + mask, softmax ------------------
    f32x4 sacc[2][8];
#pragma unroll
    for (int mf = 0; mf < 2; ++mf)
#pragma unroll
        for (int nf = 0; nf < 8; ++nf) sacc[mf][nf] = (f32x4)0.0f;

#pragma unroll
    for (int kb = 0; kb < 2; ++kb) {
        bf16x8 a[2], b[8];
#pragma unroll
        for (int mf = 0; mf < 2; ++mf)
            a[mf] = *(const bf16x8*)(q_lds + (wave * 32 + mf * 16 + lrow) * QK_STRIDE + kb * 32 + lgrp * 8);
#pragma unroll
        for (int nf = 0; nf < 8; ++nf)
            b[nf] = *(const bf16x8*)(k_lds + (nf * 16 + lrow) * QK_STRIDE + kb * 32 + lgrp * 8);
#pragma unroll
        for (int mf = 0; mf < 2; ++mf)
#pragma unroll
            for (int nf = 0; nf < 8; ++nf)
                sacc[mf][nf] = MFMA16(a[mf], b[nf], sacc[mf][nf]);
    }

    // mask add + row softmax (registers + shfl only)
    const float* mbase = adj + ((size_t)(bidx * NH + h)) * F_W * F_W;
#pragma unroll
    for (int mf = 0; mf < 2; ++mf) {
#pragma unroll
        for (int j = 0; j < 4; ++j) {
            int row = wave * 32 + mf * 16 + lgrp * 4 + j;
            const float* mrow = mbase + (size_t)row * F_W;
            float mx = -1e30f;
#pragma unroll
            for (int nf = 0; nf < 8; ++nf) {
                sacc[mf][nf][j] += mrow[nf * 16 + lrow];
                mx = fmaxf(mx, sacc[mf][nf][j]);
            }
#pragma unroll
            for (int d = 1; d < 16; d <<= 1) mx = fmaxf(mx, __shfl_xor(mx, d));
            float sum = 0.f;
#pragma unroll
            for (int nf = 0; nf < 8; ++nf) {
                float p = exp2f((sacc[mf][nf][j] - mx) * 1.44269504f);
                sacc[mf][nf][j] = p;
                sum += p;
            }
#pragma unroll
            for (int d = 1; d < 16; d <<= 1) sum += __shfl_xor(sum, d);
            float r = 1.0f / sum;
#pragma unroll
            for (int nf = 0; nf < 8; ++nf) sacc[mf][nf][j] *= r;
        }
    }
    __syncthreads();  // all waves done reading q/k -> safe to overwrite with P
#pragma unroll
    for (int mf = 0; mf < 2; ++mf)
#pragma unroll
        for (int nf = 0; nf < 8; ++nf)
#pragma unroll
            for (int j = 0; j < 4; ++j) {
                int row = wave * 32 + mf * 16 + lgrp * 4 + j;
                p_lds[row * P_STRIDE + nf * 16 + lrow] = (bf16_t)sacc[mf][nf][j];
            }
    __syncthreads();

    // ---------------- Phase C: O = P @ V (M=128, N=64, K=128) --------------
    f32x4 oacc[2][4];
#pragma unroll
    for (int mf = 0; mf < 2; ++mf)
#pragma unroll
        for (int nf = 0; nf < 4; ++nf) oacc[mf][nf] = (f32x4)0.0f;

#pragma unroll
    for (int kb = 0; kb < 4; ++kb) {
        bf16x8 a[2], b[4];
#pragma unroll
        for (int mf = 0; mf < 2; ++mf)
            a[mf] = *(const bf16x8*)(p_lds + (wave * 32 + mf * 16 + lrow) * P_STRIDE + kb * 32 + lgrp * 8);
#pragma unroll
        for (int nf = 0; nf < 4; ++nf)
            b[nf] = *(const bf16x8*)(vt_lds + (nf * 16 + lrow) * VT_STRIDE + kb * 32 + lgrp * 8);
#pragma unroll
        for (int mf = 0; mf < 2; ++mf)
#pragma unroll
            for (int nf = 0; nf < 4; ++nf)
                oacc[mf][nf] = MFMA16(a[mf], b[nf], oacc[mf][nf]);
    }

    bf16_t* obase = attn_out + (size_t)w * F_W * ED + h * HD;
#pragma unroll
    for (int mf = 0; mf < 2; ++mf)
#pragma unroll
        for (int nf = 0; nf < 4; ++nf)
#pragma unroll
            for (int j = 0; j < 4; ++j) {
                int row = wave * 32 + mf * 16 + lgrp * 4 + j;
                obase[(size_t)row * ED + nf * 16 + lrow] = (bf16_t)oacc[mf][nf][j];
            }
}

// ---------------- output projection GEMM: [65536,512]@[512,512]+b ----------
__global__ __launch_bounds__(256) void proj_kernel(
    const bf16_t* __restrict__ a_g,   // attn_out [65536][512] bf16
    const bf16_t* __restrict__ bt_g,  // proj_wt  [512][512] bf16 (n-major)
    const float* __restrict__ bias,   // [512]
    float* __restrict__ out) {        // [65536][512] fp32
    __shared__ bf16_t a_s[128 * XS_STRIDE];
    __shared__ bf16_t b_s[128 * XS_STRIDE];
    const int tid = threadIdx.x;
    const int wave = tid >> 6, lane = tid & 63;
    const int lrow = lane & 15, lgrp = lane >> 4;
    const int mtile = blockIdx.x >> 2, ntile = blockIdx.x & 3;
    const size_t m0 = (size_t)mtile * 128;
    const int n0 = ntile * 128;

    f32x4 acc[2][8];
#pragma unroll
    for (int mf = 0; mf < 2; ++mf)
#pragma unroll
        for (int nf = 0; nf < 8; ++nf) acc[mf][nf] = (f32x4)0.0f;

    for (int kc = 0; kc < 16; ++kc) {
        const int k0 = kc * 32;
        __syncthreads();
#pragma unroll
        for (int i = 0; i < 2; ++i) {
            int linear = tid + i * 256;  // [0,512)
            int row = linear >> 2, seg = linear & 3;
            *(bf16x8*)(a_s + row * XS_STRIDE + seg * 8) =
                *(const bf16x8*)(a_g + (m0 + row) * 512 + k0 + seg * 8);
            *(bf16x8*)(b_s + row * XS_STRIDE + seg * 8) =
                *(const bf16x8*)(bt_g + (size_t)(n0 + row) * 512 + k0 + seg * 8);
        }
        __syncthreads();
        bf16x8 a[2], b[8];
#pragma unroll
        for (int mf = 0; mf < 2; ++mf)
            a[mf] = *(const bf16x8*)(a_s + (wave * 32 + mf * 16 + lrow) * XS_STRIDE + lgrp * 8);
#pragma unroll
        for (int nf = 0; nf < 8; ++nf)
            b[nf] = *(const bf16x8*)(b_s + (nf * 16 + lrow) * XS_STRIDE + lgrp * 8);
#pragma unroll
        for (int mf = 0; mf < 2; ++mf)
#pragma unroll
            for (int nf = 0; nf < 8; ++nf)
                acc[mf][nf] = MFMA16(a[mf], b[nf], acc[mf][nf]);
    }

#pragma unroll
    for (int nf = 0; nf < 8; ++nf) {
        int col = n0 + nf * 16 + lrow;
        float bv = bias[col];
#pragma unroll
        for (int mf = 0; mf < 2; ++mf)
#pragma unroll
            for (int j = 0; j < 4; ++j) {
                size_t row = m0 + wave * 32 + mf * 16 + lgrp * 4 + j;
                out[row * 512 + col] = acc[mf][nf][j] + bv;
            }
    }
}

extern "C" void kernel_launch(void* const* d_in, const int* in_sizes, int n_in,
                              void* d_out, int out_size, void* d_ws, size_t ws_size,
                              hipStream_t stream) {
    const float* x      = (const float*)d_in[0];
    const float* adj    = (const float*)d_in[1];
    const float* qkv_w  = (const float*)d_in[2];
    const float* qkv_b  = (const float*)d_in[3];
    const float* proj_w = (const float*)d_in[4];
    const float* proj_b = (const float*)d_in[5];
    float* out = (float*)d_out;

    // workspace layout (bytes): attn_out bf16 64MB | qkv_wt 1.5MB | proj_wt 0.5MB
    bf16_t* attn_out = (bf16_t*)d_ws;
    bf16_t* qkv_wt   = attn_out + (size_t)B_NW * F_W * ED;  // 33,554,432 elems
    bf16_t* proj_wt  = qkv_wt + 1536 * 512;

    prep_kernel<<<3072, 256, 0, stream>>>(qkv_w, proj_w, qkv_wt, proj_wt);
    fused_attn_kernel<<<B_NW * NH, 256, 0, stream>>>(x, adj, qkv_b, qkv_wt, attn_out);
    proj_kernel<<<(B_NW * F_W / 128) * (ED / 128), 256, 0, stream>>>(attn_out, proj_wt, proj_b, out);
}